// Round 3
// baseline (416.933 us; speedup 1.0000x reference)
//
#include <hip/hip_runtime.h>
#include <hip/hip_bf16.h>
#include <cstdint>

#define IN_CH 512
#define OUT_CH 512
#define STYLE_DIM 512
#define BATCH 8
#define HW 64

typedef __bf16 bf16x8 __attribute__((ext_vector_type(8)));
typedef float f32x16 __attribute__((ext_vector_type(16)));

__device__ __forceinline__ void gload_lds16(const void* g, void* l) {
  __builtin_amdgcn_global_load_lds(
      (const __attribute__((address_space(1))) unsigned int*)g,
      (__attribute__((address_space(3))) unsigned int*)l,
      16, 0, 0);
}

#define WAITV(N) asm volatile("s_waitcnt vmcnt(" #N ")" ::: "memory")
#define LGKM0()  asm volatile("s_waitcnt lgkmcnt(0)" ::: "memory")
#define BARRIER() do { asm volatile("" ::: "memory"); __builtin_amdgcn_s_barrier(); \
                       asm volatile("" ::: "memory"); } while (0)

// ---------------- prepass 1: s[b][ic] = style @ (modw*lin_scale)^T + bias ----------------
__global__ void k_style(const float* __restrict__ style, const float* __restrict__ modw,
                        const float* __restrict__ modb, float* __restrict__ s_out) {
  __shared__ float st[BATCH * STYLE_DIM];
  const int tid = threadIdx.x;
  for (int i = tid; i < BATCH * STYLE_DIM; i += 256) st[i] = style[i];
  __syncthreads();
  const int ic = blockIdx.x * 4 + (tid >> 6);
  const int l = tid & 63;
  const float* mr = modw + (size_t)ic * STYLE_DIM + l * 8;
  float m[8];
  #pragma unroll
  for (int j = 0; j < 8; ++j) m[j] = mr[j];
  float accs[8];
  #pragma unroll
  for (int b = 0; b < 8; ++b) {
    const float* sb = st + b * STYLE_DIM + l * 8;
    float a = 0.f;
    #pragma unroll
    for (int j = 0; j < 8; ++j) a += m[j] * sb[j];
    accs[b] = a;
  }
  #pragma unroll
  for (int off = 32; off; off >>= 1) {
    #pragma unroll
    for (int b = 0; b < 8; ++b) accs[b] += __shfl_down(accs[b], off, 64);
  }
  if (l == 0) {
    #pragma unroll
    for (int b = 0; b < 8; ++b)
      s_out[b * IN_CH + ic] = accs[b] * 0.04419417382415922f + modb[ic];
  }
}

// ---------------- prepass 2: wsq[oc][ic] = sum_t W^2 ; Wb[t][oc][ic^swz] = bf16(W) ------
__global__ void k_wprep(const float* __restrict__ w, float* __restrict__ wsq,
                        __bf16* __restrict__ wb) {
  const int idx = blockIdx.x * 256 + threadIdx.x;  // 262144
  const int oc = idx >> 9, ic = idx & 511;
  const float* p = w + ((size_t)oc * IN_CH + ic) * 9;
  const int icw = ic ^ ((oc & 7) << 3);
  float sum = 0.f;
  #pragma unroll
  for (int t = 0; t < 9; ++t) {
    float v = p[t];
    sum += v * v;
    wb[((size_t)(t * OUT_CH) + oc) * IN_CH + icw] = (__bf16)v;
  }
  wsq[oc * IN_CH + ic] = sum;
}

// ---------------- prepass 3: scale[b][oc] = rsqrt(cs^2*sum(s^2*wsq)+eps)*cs --------------
__global__ void k_demod(const float* __restrict__ s, const float* __restrict__ wsq,
                        float* __restrict__ scale) {
  const int oc = blockIdx.x;
  const int l = threadIdx.x;
  const float* wr = wsq + (size_t)oc * IN_CH + l * 8;
  float w8[8];
  #pragma unroll
  for (int j = 0; j < 8; ++j) w8[j] = wr[j];
  #pragma unroll
  for (int b = 0; b < 8; ++b) {
    const float* sb = s + b * IN_CH + l * 8;
    float acc = 0.f;
    #pragma unroll
    for (int j = 0; j < 8; ++j) { float sv = sb[j]; acc += sv * sv * w8[j]; }
    #pragma unroll
    for (int off = 32; off; off >>= 1) acc += __shfl_down(acc, off, 64);
    if (l == 0)
      scale[b * OUT_CH + oc] =
          rsqrtf(acc * (1.0f / 4608.0f) + 1e-8f) * 0.014731391274719732f;
  }
}

// ---------------- prepass 4: xg[b][ug][y][x][8] = bf16(x * s), ug = ic/8 -----------------
__global__ void k_xprep(const float* __restrict__ x, const float* __restrict__ s,
                        __bf16* __restrict__ xg) {
  const int b = blockIdx.x >> 6, y = blockIdx.x & 63;   // 512 blocks
  const int w = threadIdx.x >> 6, lane = threadIdx.x & 63;
  const float* sr = s + b * IN_CH;
  #pragma unroll
  for (int it = 0; it < 8; ++it) {
    const int ug = it * 8 + w;
    bf16x8 pk;
    #pragma unroll
    for (int j = 0; j < 8; ++j) {
      const int ic = ug * 8 + j;
      pk[j] = (__bf16)(x[(((size_t)(b * IN_CH) + ic) * HW + y) * HW + lane] * sr[ic]);
    }
    *(bf16x8*)(xg + ((((size_t)(b * 64 + ug) * HW + y) * HW + lane) * 8)) = pk;
  }
}

// ---------------- main: implicit-GEMM conv, 4 waves, wave tile 128x128 -------------------
// block 256 oc x 256 px; LDS reads/MFMA = 0.5 (vs 0.75 at 128x64) -> LDS-BW relief
__global__ __launch_bounds__(256, 1) void k_conv(
    const __bf16* __restrict__ Wg,   // [9][512][512] ic pre-swizzled by (oc&7)
    const __bf16* __restrict__ Xg,   // [8][64 ug][64 y][64 x][8] plain
    const float* __restrict__ scale, // [8][512] = demod*cs
    float* __restrict__ out)         // [8][512][64][64]
{
  __shared__ __attribute__((aligned(16))) __bf16 Xs[6 * 66 * 64];   // 50688 B
  __shared__ __attribute__((aligned(16))) __bf16 Wl[3][256 * 64];   // 98304 B

  const int tid = threadIdx.x;
  const int lane = tid & 63;
  const int wv = tid >> 6;      // wave 0..3
  const int wm = wv >> 1;       // 0..1 : oc half
  const int wn = wv & 1;        // 0..1 : pixel half (2 image rows)
  const int ln31 = lane & 31;
  const int laneK = lane >> 5;

  // XCD-chunked swizzle: XCD x gets all 32 blocks of batch x
  const int bid0 = blockIdx.x;
  const int bid = (bid0 & 7) * 32 + (bid0 >> 3);
  const int octile = bid & 1;
  const int ptile = (bid >> 1) & 15;
  const int b = bid >> 5;
  const int oc0 = octile * 256;
  const int r0 = ptile * 4;

  auto stage_w = [&](int chunk, int tap, int bsel) {  // 8 gload_lds per thread (32 KB)
    const int ic0 = chunk * 64;
    #pragma unroll
    for (int i = 0; i < 8; ++i) {
      const int sidx = tid + 256 * i;
      const int oc = sidx >> 3, u = sidx & 7;
      gload_lds16(Wg + (((size_t)(tap * OUT_CH) + oc0 + oc) * IN_CH + ic0 + u * 8),
                  &Wl[bsel][oc * 64 + u * 8]);
    }
  };

  bf16x8 xr[12];
  const int xx = lane;                 // global x column handled by this lane
  auto xload = [&](int chunk) {        // 12 global_load_dwordx4 -> regs (T14 issue-early)
    #pragma unroll
    for (int j = 0; j < 12; ++j) {
      const int row = j >> 1, half = j & 1;
      const int y = r0 - 1 + row;
      if (y >= 0 && y < HW) {
        const int ug = chunk * 8 + half * 4 + wv;
        xr[j] = *(const bf16x8*)(Xg + ((((size_t)(b * 64 + ug) * HW + y) * HW + xx) * 8));
      }
    }
  };
  auto xwrite = [&]() {                // 12 swizzled ds_write_b128 (write-late)
    const int key = (xx + 1) & 7;
    #pragma unroll
    for (int j = 0; j < 12; ++j) {
      const int row = j >> 1, half = j & 1;
      const int y = r0 - 1 + row;
      if (y >= 0 && y < HW) {
        const int u = half * 4 + wv;
        *(bf16x8*)(&Xs[(row * 66 + xx + 1) * 64 + ((u ^ key) << 3)]) = xr[j];
      }
    }
  };

  // prologue: start memory early, zero Xs (halo = conv zero-padding), publish X0
  xload(0);                 // queue: X(12)
  stage_w(0, 0, 0);         // + W0(8)
  stage_w(0, 1, 1);         // + W1(8)
  {
    float4 z = {0.f, 0.f, 0.f, 0.f};
    float4* p = (float4*)Xs;
    for (int i = tid; i < 6 * 66 * 64 / 8; i += 256) p[i] = z;
  }
  __syncthreads();
  WAITV(16);                // X landed; W0,W1 in flight
  xwrite();
  LGKM0();
  BARRIER();

  f32x16 acc[4][4] = {};
  const int akey8 = (ln31 & 7) << 3;
  const int kb = laneK * 8;

  int tap = 0, chunk = 0, buf = 0;

  for (int s = 0; s < 72; ++s) {
    if (s + 2 < 72) {                       // 2-deep W prefetch into (buf+2)%3
      int t2 = tap + 2, c2 = chunk, b2 = buf + 2;
      if (t2 >= 9) { t2 -= 9; ++c2; }
      if (b2 >= 3) b2 -= 3;
      stage_w(c2, t2, b2);
    }
    if (tap == 6 && chunk < 7) xload(chunk + 1);   // X->regs, hides HBM latency

    // counted waits: drain only W(s) (front 8); keep later tiles in flight
    if (tap >= 6 && chunk < 7) { WAITV(28); }      // [W(s)|X,Wn..] = 36 -> 28
    else if (s == 70) { WAITV(8); }
    else if (s == 71) { WAITV(0); }
    else { WAITV(16); }                            // [W(s),W(s+1),W(s+2)] = 24 -> 16
    BARRIER();

    const int dy = tap / 3 - 1, dx = tap % 3 - 1;
    const int col0 = ln31 + 1 + dx;
    const int bkey8 = (col0 & 7) << 3;
    const __bf16* __restrict__ wb0 = &Wl[buf][(wm * 128 + ln31) * 64];
    const __bf16* xb[4];
    #pragma unroll
    for (int nf = 0; nf < 4; ++nf)
      xb[nf] = &Xs[((wn * 2 + (nf >> 1) + 1 + dy) * 66 + (nf & 1) * 32 + col0) * 64];

    #pragma unroll
    for (int ks = 0; ks < 4; ++ks) {
      const int ael = (ks * 16 + kb) ^ akey8;
      const int bel = (ks * 16 + kb) ^ bkey8;
      bf16x8 av[4], bv[4];
      #pragma unroll
      for (int mf = 0; mf < 4; ++mf) av[mf] = *(const bf16x8*)(wb0 + mf * 2048 + ael);
      #pragma unroll
      for (int nf = 0; nf < 4; ++nf) bv[nf] = *(const bf16x8*)(xb[nf] + bel);
      #pragma unroll
      for (int mf = 0; mf < 4; ++mf) {
        #pragma unroll
        for (int nf = 0; nf < 4; ++nf)
          acc[mf][nf] = __builtin_amdgcn_mfma_f32_32x32x16_bf16(av[mf], bv[nf], acc[mf][nf], 0, 0, 0);
      }
    }
    BARRIER();   // all waves done reading Wl[buf] & Xs before restage

    if (tap == 8 && chunk < 7) {            // publish X(chunk+1)
      WAITV(16);                            // drain X regs; keep Wn0,Wn1 in flight
      xwrite();
      LGKM0();
      BARRIER();
    }
    if (++tap == 9) { tap = 0; ++chunk; }
    if (++buf == 3) buf = 0;
  }

  // epilogue: out = acc * (demod*cs), NCHW
  const int y0 = r0 + wn * 2;
  #pragma unroll
  for (int mf = 0; mf < 4; ++mf) {
    #pragma unroll
    for (int reg = 0; reg < 16; ++reg) {
      const int rowid = (reg & 3) + 8 * (reg >> 2) + 4 * laneK;
      const int oc = oc0 + wm * 128 + mf * 32 + rowid;
      const float sc = scale[b * OUT_CH + oc];
      float* obase = out + (size_t)(b * OUT_CH + oc) * (HW * HW);
      #pragma unroll
      for (int nf = 0; nf < 4; ++nf)
        obase[(y0 + (nf >> 1)) * HW + (nf & 1) * 32 + ln31] = acc[mf][nf][reg] * sc;
    }
  }
}

// ---------------- launcher ---------------------------------------------------------------
extern "C" void kernel_launch(void* const* d_in, const int* in_sizes, int n_in,
                              void* d_out, int out_size, void* d_ws, size_t ws_size,
                              hipStream_t stream) {
  const float* x      = (const float*)d_in[0];
  const float* style  = (const float*)d_in[1];
  const float* weight = (const float*)d_in[2];
  const float* modw   = (const float*)d_in[3];
  const float* modb   = (const float*)d_in[4];
  float* out = (float*)d_out;

  char* ws = (char*)d_ws;
  float*  s_buf = (float*)(ws + 0);
  float*  scale = (float*)(ws + 16384);
  float*  wsq   = (float*)(ws + 32768);
  __bf16* wb    = (__bf16*)(ws + 32768 + 1048576);
  __bf16* xg    = (__bf16*)(ws + 32768 + 1048576 + 9 * OUT_CH * IN_CH * 2);

  k_style<<<128, 256, 0, stream>>>(style, modw, modb, s_buf);
  k_wprep<<<1024, 256, 0, stream>>>(weight, wsq, wb);
  k_demod<<<512, 64, 0, stream>>>(s_buf, wsq, scale);
  k_xprep<<<BATCH * HW, 512, 0, stream>>>(x, s_buf, xg);
  k_conv<<<256, 256, 0, stream>>>(wb, xg, scale, out);
}

// Round 4
// 183.929 us; speedup vs baseline: 2.2668x; 2.2668x over previous
//
#include <hip/hip_runtime.h>
#include <hip/hip_bf16.h>
#include <cstdint>

#define IN_CH 512
#define OUT_CH 512
#define STYLE_DIM 512
#define BATCH 8
#define HW 64

typedef __bf16 bf16x8 __attribute__((ext_vector_type(8)));
typedef float f32x16 __attribute__((ext_vector_type(16)));

__device__ __forceinline__ void gload_lds16(const void* g, void* l) {
  __builtin_amdgcn_global_load_lds(
      (const __attribute__((address_space(1))) unsigned int*)g,
      (__attribute__((address_space(3))) unsigned int*)l,
      16, 0, 0);
}

#define WAITV(N) asm volatile("s_waitcnt vmcnt(" #N ")" ::: "memory")
#define BARRIER() do { asm volatile("" ::: "memory"); __builtin_amdgcn_s_barrier(); \
                       asm volatile("" ::: "memory"); } while (0)

// ---------------- prepass 1: s[b][ic] = style @ (modw*lin_scale)^T + bias ----------------
__global__ void k_style(const float* __restrict__ style, const float* __restrict__ modw,
                        const float* __restrict__ modb, float* __restrict__ s_out) {
  __shared__ float st[BATCH * STYLE_DIM];
  const int tid = threadIdx.x;
  for (int i = tid; i < BATCH * STYLE_DIM; i += 256) st[i] = style[i];
  __syncthreads();
  const int ic = blockIdx.x * 4 + (tid >> 6);
  const int l = tid & 63;
  const float* mr = modw + (size_t)ic * STYLE_DIM + l * 8;
  float m[8];
  #pragma unroll
  for (int j = 0; j < 8; ++j) m[j] = mr[j];
  float accs[8];
  #pragma unroll
  for (int b = 0; b < 8; ++b) {
    const float* sb = st + b * STYLE_DIM + l * 8;
    float a = 0.f;
    #pragma unroll
    for (int j = 0; j < 8; ++j) a += m[j] * sb[j];
    accs[b] = a;
  }
  #pragma unroll
  for (int off = 32; off; off >>= 1) {
    #pragma unroll
    for (int b = 0; b < 8; ++b) accs[b] += __shfl_down(accs[b], off, 64);
  }
  if (l == 0) {
    #pragma unroll
    for (int b = 0; b < 8; ++b)
      s_out[b * IN_CH + ic] = accs[b] * 0.04419417382415922f + modb[ic];
  }
}

// ---------------- prepass 2: wsq[oc][ic] = sum_t W^2 ; Wb[t][oc][ic^swz] = bf16(W) ------
__global__ void k_wprep(const float* __restrict__ w, float* __restrict__ wsq,
                        __bf16* __restrict__ wb) {
  const int idx = blockIdx.x * 256 + threadIdx.x;  // 262144
  const int oc = idx >> 9, ic = idx & 511;
  const float* p = w + ((size_t)oc * IN_CH + ic) * 9;
  const int icw = ic ^ ((oc & 7) << 3);
  float sum = 0.f;
  #pragma unroll
  for (int t = 0; t < 9; ++t) {
    float v = p[t];
    sum += v * v;
    wb[((size_t)(t * OUT_CH) + oc) * IN_CH + icw] = (__bf16)v;
  }
  wsq[oc * IN_CH + ic] = sum;
}

// ---------------- prepass 3: scale[b][oc] = rsqrt(cs^2*sum(s^2*wsq)+eps)*cs --------------
__global__ void k_demod(const float* __restrict__ s, const float* __restrict__ wsq,
                        float* __restrict__ scale) {
  const int oc = blockIdx.x;
  const int l = threadIdx.x;
  const float* wr = wsq + (size_t)oc * IN_CH + l * 8;
  float w8[8];
  #pragma unroll
  for (int j = 0; j < 8; ++j) w8[j] = wr[j];
  #pragma unroll
  for (int b = 0; b < 8; ++b) {
    const float* sb = s + b * IN_CH + l * 8;
    float acc = 0.f;
    #pragma unroll
    for (int j = 0; j < 8; ++j) { float sv = sb[j]; acc += sv * sv * w8[j]; }
    #pragma unroll
    for (int off = 32; off; off >>= 1) acc += __shfl_down(acc, off, 64);
    if (l == 0)
      scale[b * OUT_CH + oc] =
          rsqrtf(acc * (1.0f / 4608.0f) + 1e-8f) * 0.014731391274719732f;
  }
}

// ---------------- prepass 4: xg[b][ug][y][x][8] = bf16(x * s), ug = ic/8 -----------------
__global__ void k_xprep(const float* __restrict__ x, const float* __restrict__ s,
                        __bf16* __restrict__ xg) {
  const int b = blockIdx.x >> 6, y = blockIdx.x & 63;   // 512 blocks
  const int w = threadIdx.x >> 6, lane = threadIdx.x & 63;
  const float* sr = s + b * IN_CH;
  #pragma unroll
  for (int it = 0; it < 8; ++it) {
    const int ug = it * 8 + w;
    bf16x8 pk;
    #pragma unroll
    for (int j = 0; j < 8; ++j) {
      const int ic = ug * 8 + j;
      pk[j] = (__bf16)(x[(((size_t)(b * IN_CH) + ic) * HW + y) * HW + lane] * sr[ic]);
    }
    *(bf16x8*)(xg + ((((size_t)(b * 64 + ug) * HW + y) * HW + lane) * 8)) = pk;
  }
}

// ---------------- main: implicit-GEMM conv, 4 waves, wave tile 128x128, all-gload_lds ----
// LDS reads/MFMA = 0.5; per-CU-tap LDS 1536 cyc < MFMA 2048 cyc -> MFMA-bound design
__global__ __launch_bounds__(256, 1) void k_conv(
    const __bf16* __restrict__ Wg,   // [9][512][512] ic pre-swizzled by (oc&7)
    const __bf16* __restrict__ Xg,   // [8][64 ug][64 y][64 x][8] plain
    const float* __restrict__ scale, // [8][512] = demod*cs
    float* __restrict__ out)         // [8][512][64][64]
{
  __shared__ __attribute__((aligned(16))) __bf16 Xs[6 * 66 * 64];   // 50688 B
  __shared__ __attribute__((aligned(16))) __bf16 Wl[3][256 * 64];   // 98304 B
  __shared__ __attribute__((aligned(16))) __bf16 Dump[2048];        // 4096 B vmcnt-pad sink

  const int tid = threadIdx.x;
  const int lane = tid & 63;
  const int wv = tid >> 6;      // wave 0..3
  const int wm = wv >> 1;       // oc half
  const int wn = wv & 1;        // pixel half (2 image rows)
  const int ln31 = lane & 31;
  const int laneK = lane >> 5;

  const int bid0 = blockIdx.x;
  const int bid = (bid0 & 7) * 32 + (bid0 >> 3);   // XCD-chunked swizzle
  const int octile = bid & 1;
  const int ptile = (bid >> 1) & 15;
  const int b = bid >> 5;
  const int oc0 = octile * 256;
  const int r0 = ptile * 4;

  auto stage_w = [&](int chunk, int tap, int bsel) {  // 8 gload_lds16 per thread (32 KB)
    const int ic0 = chunk * 64;
    #pragma unroll
    for (int i = 0; i < 8; ++i) {
      const int sidx = tid + 256 * i;
      const int oc = sidx >> 3, u = sidx & 7;
      gload_lds16(Wg + (((size_t)(tap * OUT_CH) + oc0 + oc) * IN_CH + ic0 + u * 8),
                  &Wl[bsel][oc * 64 + u * 8]);
    }
  };
  auto stage_x = [&](int chunk) {   // ALWAYS 12 gload_lds16 per thread (vmcnt bookkeeping)
    #pragma unroll
    for (int j = 0; j < 12; ++j) {
      const int row = j >> 1;
      const int col = (j & 1) * 32 + (tid >> 3);
      const int u = tid & 7;
      const int y = r0 - 1 + row;
      const bool ok = (y >= 0 && y < HW);
      const int yc = ok ? y : (y < 0 ? 0 : HW - 1);
      const int ug = chunk * 8 + (u ^ ((col + 1) & 7));   // swizzle via global src addr
      void* dst = ok ? (void*)&Xs[(row * 66 + col + 1) * 64 + u * 8]
                     : (void*)&Dump[((tid & 63) * 8) | ((tid >> 6) << 9)];
      gload_lds16(Xg + ((((size_t)(b * 64 + ug) * HW + yc) * HW + col) * 8), dst);
    }
  };

  // zero Xs first (halo rows/cols = conv zero-padding), THEN start async staging
  {
    float4 z = {0.f, 0.f, 0.f, 0.f};
    float4* p = (float4*)Xs;
    for (int i = tid; i < 6 * 66 * 64 / 8; i += 256) p[i] = z;
  }
  __syncthreads();
  stage_x(0);               // queue: X0(12)
  stage_w(0, 0, 0);         // + W0(8)
  stage_w(0, 1, 1);         // + W1(8) = 28
  WAITV(8);                 // drain X0+W0; W1 in flight
  BARRIER();

  f32x16 acc[4][4] = {};
  const int akey8 = (ln31 & 7) << 3;
  const int kb = laneK * 8;

  int tap = 0, chunk = 0, buf = 0;

  for (int s = 0; s < 72; ++s) {
    if (s + 2 < 72) {                       // 2-deep W prefetch into (buf+2)%3
      int t2 = tap + 2, c2 = chunk, b2 = buf + 2;
      if (t2 >= 9) { t2 -= 9; ++c2; }
      if (b2 >= 3) b2 -= 3;
      stage_w(c2, t2, b2);
    }
    // counted waits (hand-derived; see journal): steady leaves [W(s+1),W(s+2)]=16
    if (s == 70)                 { WAITV(8); }
    else if (s == 71)            { WAITV(0); }
    else if (tap == 0 && s > 0)  { WAITV(8); }   // drains W(s)+X(chunk); leaves W(s+2)
    else                         { WAITV(16); }  // drains W(s)
    BARRIER();

    const int dy = tap / 3 - 1, dx = tap % 3 - 1;
    const int col0 = ln31 + 1 + dx;
    const int bkey8 = (col0 & 7) << 3;      // +32 col half doesn't change &7
    const __bf16* __restrict__ wbase = &Wl[buf][(wm * 128 + ln31) * 64];
    const __bf16* xb[4];
    #pragma unroll
    for (int nf = 0; nf < 4; ++nf)
      xb[nf] = &Xs[((wn * 2 + (nf >> 1) + 1 + dy) * 66 + (nf & 1) * 32 + col0) * 64];

    #pragma unroll
    for (int ks = 0; ks < 4; ++ks) {
      const int ael = (ks * 16 + kb) ^ akey8;
      const int bel = (ks * 16 + kb) ^ bkey8;
      bf16x8 av[4], bv[4];
      #pragma unroll
      for (int mf = 0; mf < 4; ++mf) av[mf] = *(const bf16x8*)(wbase + mf * 2048 + ael);
      #pragma unroll
      for (int nf = 0; nf < 4; ++nf) bv[nf] = *(const bf16x8*)(xb[nf] + bel);
      #pragma unroll
      for (int mf = 0; mf < 4; ++mf) {
        #pragma unroll
        for (int nf = 0; nf < 4; ++nf)
          acc[mf][nf] = __builtin_amdgcn_mfma_f32_32x32x16_bf16(av[mf], bv[nf], acc[mf][nf], 0, 0, 0);
      }
    }
    BARRIER();   // all waves done reading Wl[buf]/Xs before restage lands

    if (tap == 8 && chunk < 7) stage_x(chunk + 1);  // async; drained at next tap0 WAITV(8)

    if (++tap == 9) { tap = 0; ++chunk; }
    if (++buf == 3) buf = 0;
  }

  // epilogue: out = acc * (demod*cs), NCHW
  const int y0 = r0 + wn * 2;
  #pragma unroll
  for (int mf = 0; mf < 4; ++mf) {
    #pragma unroll
    for (int reg = 0; reg < 16; ++reg) {
      const int rowid = (reg & 3) + 8 * (reg >> 2) + 4 * laneK;
      const int oc = oc0 + wm * 128 + mf * 32 + rowid;
      const float sc = scale[b * OUT_CH + oc];
      float* obase = out + (size_t)(b * OUT_CH + oc) * (HW * HW);
      #pragma unroll
      for (int nf = 0; nf < 4; ++nf)
        obase[(y0 + (nf >> 1)) * HW + (nf & 1) * 32 + ln31] = acc[mf][nf][reg] * sc;
    }
  }
}

// ---------------- launcher ---------------------------------------------------------------
extern "C" void kernel_launch(void* const* d_in, const int* in_sizes, int n_in,
                              void* d_out, int out_size, void* d_ws, size_t ws_size,
                              hipStream_t stream) {
  const float* x      = (const float*)d_in[0];
  const float* style  = (const float*)d_in[1];
  const float* weight = (const float*)d_in[2];
  const float* modw   = (const float*)d_in[3];
  const float* modb   = (const float*)d_in[4];
  float* out = (float*)d_out;

  char* ws = (char*)d_ws;
  float*  s_buf = (float*)(ws + 0);
  float*  scale = (float*)(ws + 16384);
  float*  wsq   = (float*)(ws + 32768);
  __bf16* wb    = (__bf16*)(ws + 32768 + 1048576);
  __bf16* xg    = (__bf16*)(ws + 32768 + 1048576 + 9 * OUT_CH * IN_CH * 2);

  k_style<<<128, 256, 0, stream>>>(style, modw, modb, s_buf);
  k_wprep<<<1024, 256, 0, stream>>>(weight, wsq, wb);
  k_demod<<<512, 64, 0, stream>>>(s_buf, wsq, scale);
  k_xprep<<<BATCH * HW, 512, 0, stream>>>(x, s_buf, xg);
  k_conv<<<256, 256, 0, stream>>>(wb, xg, scale, out);
}